// Round 5
// baseline (429.869 us; speedup 1.0000x reference)
//
#include <hip/hip_runtime.h>
#include <math.h>

#define NU_F 0.0031830988618379067f

typedef __bf16 bf16x8 __attribute__((ext_vector_type(8)));
typedef float  f32x4  __attribute__((ext_vector_type(4)));

__device__ __forceinline__ float fast_tanh(float z) {
    float e = __expf(2.0f * z);
    return 1.0f - 2.0f / (e + 1.0f);
}

// Pack truncated-bf16 hi halves of (a,b) -> one u32: {b.hi16, a.hi16}
__device__ __forceinline__ unsigned pack_hi(float a, float b) {
    return __builtin_amdgcn_perm(__float_as_uint(b), __float_as_uint(a), 0x07060302u);
}
// Pack bf16(lo) of (a,b) where lo = v - trunc16(v)
__device__ __forceinline__ unsigned pack_lo(float a, float b) {
    float ra = a - __uint_as_float(__float_as_uint(a) & 0xffff0000u);
    float rb = b - __uint_as_float(__float_as_uint(b) & 0xffff0000u);
    __bf16 la = (__bf16)ra, lb = (__bf16)rb;
    unsigned ua = (unsigned)*(unsigned short*)&la;
    unsigned ub = (unsigned)*(unsigned short*)&lb;
    return __builtin_amdgcn_perm(ub, ua, 0x05040100u);
}

// ---------------------------------------------------------------------------
// Prep: W_hid fp32 [7][128(k)][128(c)] -> bf16 hi/lo B-fragments, fragment-
// major (each wave-load = one coalesced 1 KiB block):
//   fid = ((l*8 + nt)*2 + hl)*4 + ks ; element = fid*512 + lane*8 + jj
//   k = ks*32 + q*8 + jj, lane = q*16 + nn
//   channel map (4 adjacent channels per B-col lane):
//     nt = (c>>6)*4 + (c&3), nn = (c>>2)&15  ->  c = wv*64 + nn*4 + j
// ---------------------------------------------------------------------------
__global__ void prep_wfrag(const float* __restrict__ Whid, __bf16* __restrict__ wcf)
{
    int t = blockIdx.x * 256 + threadIdx.x;   // 0 .. 114687
    const int l = t >> 14;
    const int r = t & 16383;
    const int k = r >> 7;
    const int c = r & 127;
    const float v = Whid[t];
    const __bf16 hi = (__bf16)v;
    const __bf16 lo = (__bf16)(v - (float)hi);
    const int ks = k >> 5, q = (k >> 3) & 3, jj = k & 7;
    const int nt = ((c >> 6) << 2) | (c & 3);
    const int nn = (c >> 2) & 15;
    const int lane = q * 16 + nn;
    const int base = (((l * 8 + nt) * 8) + ks) * 512 + lane * 8 + jj;  // hl=0
    wcf[base]        = hi;
    wcf[base + 2048] = lo;                                             // hl=1
}

// ---------------------------------------------------------------------------
// Fused kernel, 128 threads = 2 waves; each wave: 4 M-tiles x 4 N-tiles.
// Blocks 0..8191: 16 deriv points (M rows = state*16+p, jets v,vx,vt,vxx).
// Blocks 8192..8319: 64 value-only points (M rows = p).
// H in LDS as packed u32 rows [64][68]. Lane owns channels wv*64+lm*4+{0..3}
// -> epilogue writes are 2x ds_write_b64 (hi) + lo; A-reads amortized over
// 4 N-tiles (halves per-CU LDS traffic vs 4-wave/2-Ntile layout).
// ---------------------------------------------------------------------------
#define HR 68

#define MFMA(A, B, C) __builtin_amdgcn_mfma_f32_16x16x32_bf16((A), (B), (C), 0, 0, 0)

__global__ __launch_bounds__(128, 2)
void pinn_fused(const float* __restrict__ xf,
                const float* __restrict__ x0,  const float* __restrict__ xbl,
                const float* __restrict__ xbr,
                const float* __restrict__ Win,  const float* __restrict__ bin,
                const float* __restrict__ bhid,
                const float* __restrict__ Wout, const float* __restrict__ bout,
                const __bf16* __restrict__ wcf,
                float* __restrict__ out)
{
    __shared__ unsigned Hhi[64 * HR];
    __shared__ unsigned Hlo[64 * HR];
    __shared__ float xpt[128];
    __shared__ float pbuf[128];
    __shared__ float dots[64];

    const int tid  = threadIdx.x;
    const int lane = tid & 63;
    const int wv   = tid >> 6;         // wave 0/1 -> N-tiles wv*4..wv*4+3
    const int lm   = lane & 15;
    const int lq   = lane >> 4;
    const int blk  = blockIdx.x;
    const bool isv = (blk >= 8192);

    if (!isv) {
        if (tid < 32) xpt[tid] = xf[blk * 32 + tid];
    } else {
        const int vb = blk - 8192;
        const float* src = (vb < 64) ? (x0 + vb * 128)
                         : (vb < 96) ? (xbl + (vb - 64) * 128)
                                     : (xbr + (vb - 96) * 128);
        xpt[tid] = src[tid];
    }
    __syncthreads();

    // ---- input layer: thread owns channel quad c = cq*4..cq*4+3 ----
    const int cq = tid & 31;
    {
        float w0v[4], w1v[4], bv[4];
        *(float4*)w0v = *(const float4*)&Win[cq * 4];
        *(float4*)w1v = *(const float4*)&Win[128 + cq * 4];
        *(float4*)bv  = *(const float4*)&bin[cq * 4];
        if (!isv) {
            const int pg = (tid >> 5) * 4;
            #pragma unroll
            for (int i = 0; i < 4; ++i) {
                const int p = pg + i;
                const float x = xpt[2 * p], tt = xpt[2 * p + 1];
                float h[4][4];   // [s][ch]
                #pragma unroll
                for (int ch = 0; ch < 4; ++ch) {
                    const float z = fmaf(x, w0v[ch], fmaf(tt, w1v[ch], bv[ch]));
                    const float y = fast_tanh(z);
                    const float d = 1.f - y * y;
                    h[0][ch] = y;
                    h[1][ch] = d * w0v[ch];
                    h[2][ch] = d * w1v[ch];
                    h[3][ch] = -2.f * y * d * w0v[ch] * w0v[ch];
                }
                #pragma unroll
                for (int s = 0; s < 4; ++s) {
                    uint2 hh;
                    hh.x = pack_hi(h[s][0], h[s][1]);
                    hh.y = pack_hi(h[s][2], h[s][3]);
                    *(uint2*)&Hhi[(s * 16 + p) * HR + cq * 2] = hh;
                }
                #pragma unroll
                for (int s = 0; s < 3; ++s) {
                    uint2 ll;
                    ll.x = pack_lo(h[s][0], h[s][1]);
                    ll.y = pack_lo(h[s][2], h[s][3]);
                    *(uint2*)&Hlo[(s * 16 + p) * HR + cq * 2] = ll;
                }
                uint2 zz; zz.x = 0u; zz.y = 0u;     // vxx lo stays 0 all layers
                *(uint2*)&Hlo[(48 + p) * HR + cq * 2] = zz;
            }
        } else {
            const int pg = (tid >> 5) * 16;
            #pragma unroll
            for (int i = 0; i < 16; ++i) {
                const int p = pg + i;
                const float x = xpt[2 * p], tt = xpt[2 * p + 1];
                float y[4];
                #pragma unroll
                for (int ch = 0; ch < 4; ++ch)
                    y[ch] = fast_tanh(fmaf(x, w0v[ch], fmaf(tt, w1v[ch], bv[ch])));
                uint2 hh, ll;
                hh.x = pack_hi(y[0], y[1]); hh.y = pack_hi(y[2], y[3]);
                ll.x = pack_lo(y[0], y[1]); ll.y = pack_lo(y[2], y[3]);
                *(uint2*)&Hhi[p * HR + cq * 2] = hh;
                *(uint2*)&Hlo[p * HR + cq * 2] = ll;
            }
        }
    }
    __syncthreads();

    // B-fragment pointers: 4 N-tiles per wave, hi/lo contiguous blocks.
    const __bf16* pbh[4];
    const __bf16* pbl[4];
    #pragma unroll
    for (int j = 0; j < 4; ++j) {
        pbh[j] = wcf + (wv * 4 + j) * 4096 + lane * 8;
        pbl[j] = pbh[j] + 2048;
    }
    const int wc = wv * 32 + lm * 2;   // epilogue dword column (c = wv*64+lm*4)

    if (!isv) {
        // ================= derivative path =================
        for (int l = 0; l < 7; ++l) {
            f32x4 acc[4][4];   // [state][j]
            #pragma unroll
            for (int s = 0; s < 4; ++s)
                #pragma unroll
                for (int j = 0; j < 4; ++j) acc[s][j] = (f32x4){0.f, 0.f, 0.f, 0.f};

            #pragma unroll
            for (int ks = 0; ks < 4; ++ks) {
                const int ro = ks * 16 + lq * 4;
                const bf16x8 ah0 = *(const bf16x8*)&Hhi[(0 * 16 + lm) * HR + ro];
                const bf16x8 ah1 = *(const bf16x8*)&Hhi[(1 * 16 + lm) * HR + ro];
                const bf16x8 ah2 = *(const bf16x8*)&Hhi[(2 * 16 + lm) * HR + ro];
                const bf16x8 ah3 = *(const bf16x8*)&Hhi[(3 * 16 + lm) * HR + ro];
                const bf16x8 al0 = *(const bf16x8*)&Hlo[(0 * 16 + lm) * HR + ro];
                const bf16x8 al1 = *(const bf16x8*)&Hlo[(1 * 16 + lm) * HR + ro];
                const bf16x8 al2 = *(const bf16x8*)&Hlo[(2 * 16 + lm) * HR + ro];
                #pragma unroll
                for (int j = 0; j < 4; ++j) {
                    const bf16x8 bh = *(const bf16x8*)(pbh[j] + ks * 512);
                    const bf16x8 bl = *(const bf16x8*)(pbl[j] + ks * 512);
                    acc[0][j] = MFMA(ah0, bh, acc[0][j]);
                    acc[0][j] = MFMA(ah0, bl, acc[0][j]);
                    acc[0][j] = MFMA(al0, bh, acc[0][j]);
                    acc[1][j] = MFMA(ah1, bh, acc[1][j]);
                    acc[1][j] = MFMA(ah1, bl, acc[1][j]);
                    acc[1][j] = MFMA(al1, bh, acc[1][j]);
                    acc[2][j] = MFMA(ah2, bh, acc[2][j]);
                    acc[2][j] = MFMA(ah2, bl, acc[2][j]);
                    acc[2][j] = MFMA(al2, bh, acc[2][j]);
                    acc[3][j] = MFMA(ah3, bh, acc[3][j]);
                    acc[3][j] = MFMA(ah3, bl, acc[3][j]);
                }
            }
            __syncthreads();

            float bb[4];
            *(float4*)bb = *(const float4*)&bhid[l * 128 + wv * 64 + lm * 4];
            #pragma unroll
            for (int r = 0; r < 4; ++r) {
                const int p = lq * 4 + r;
                float h[4][4];   // [j][s]
                #pragma unroll
                for (int j = 0; j < 4; ++j) {
                    const float zv  = acc[0][j][r] + bb[j];
                    const float zx  = acc[1][j][r];
                    const float zt  = acc[2][j][r];
                    const float zxx = acc[3][j][r];
                    const float y = fast_tanh(zv);
                    const float d = 1.f - y * y;
                    h[j][0] = y;
                    h[j][1] = d * zx;
                    h[j][2] = d * zt;
                    h[j][3] = fmaf(d, zxx, -2.f * y * d * zx * zx);
                }
                #pragma unroll
                for (int s = 0; s < 4; ++s) {
                    uint2 hh;
                    hh.x = pack_hi(h[0][s], h[1][s]);
                    hh.y = pack_hi(h[2][s], h[3][s]);
                    *(uint2*)&Hhi[(s * 16 + p) * HR + wc] = hh;
                }
                #pragma unroll
                for (int s = 0; s < 3; ++s) {
                    uint2 ll;
                    ll.x = pack_lo(h[0][s], h[1][s]);
                    ll.y = pack_lo(h[2][s], h[3][s]);
                    *(uint2*)&Hlo[(s * 16 + p) * HR + wc] = ll;
                }
            }
            #pragma unroll
            for (int j = 0; j < 4; ++j) { pbh[j] += 32768; pbl[j] += 32768; }
            __syncthreads();
        }
    } else {
        // ================= value-only path =================
        for (int l = 0; l < 7; ++l) {
            f32x4 acc[4][4];   // [m-tile][j]
            #pragma unroll
            for (int mt = 0; mt < 4; ++mt)
                #pragma unroll
                for (int j = 0; j < 4; ++j) acc[mt][j] = (f32x4){0.f, 0.f, 0.f, 0.f};

            #pragma unroll
            for (int ks = 0; ks < 4; ++ks) {
                const int ro = ks * 16 + lq * 4;
                bf16x8 ah[4], al[4];
                #pragma unroll
                for (int mt = 0; mt < 4; ++mt) {
                    ah[mt] = *(const bf16x8*)&Hhi[(mt * 16 + lm) * HR + ro];
                    al[mt] = *(const bf16x8*)&Hlo[(mt * 16 + lm) * HR + ro];
                }
                #pragma unroll
                for (int j = 0; j < 4; ++j) {
                    const bf16x8 bh = *(const bf16x8*)(pbh[j] + ks * 512);
                    const bf16x8 bl = *(const bf16x8*)(pbl[j] + ks * 512);
                    #pragma unroll
                    for (int mt = 0; mt < 4; ++mt) {
                        acc[mt][j] = MFMA(ah[mt], bh, acc[mt][j]);
                        acc[mt][j] = MFMA(ah[mt], bl, acc[mt][j]);
                        acc[mt][j] = MFMA(al[mt], bh, acc[mt][j]);
                    }
                }
            }
            __syncthreads();

            float bb[4];
            *(float4*)bb = *(const float4*)&bhid[l * 128 + wv * 64 + lm * 4];
            #pragma unroll
            for (int mt = 0; mt < 4; ++mt) {
                #pragma unroll
                for (int r = 0; r < 4; ++r) {
                    const int p = mt * 16 + lq * 4 + r;
                    float y[4];
                    #pragma unroll
                    for (int j = 0; j < 4; ++j)
                        y[j] = fast_tanh(acc[mt][j][r] + bb[j]);
                    uint2 hh, ll;
                    hh.x = pack_hi(y[0], y[1]); hh.y = pack_hi(y[2], y[3]);
                    ll.x = pack_lo(y[0], y[1]); ll.y = pack_lo(y[2], y[3]);
                    *(uint2*)&Hhi[p * HR + wc] = hh;
                    *(uint2*)&Hlo[p * HR + wc] = ll;
                }
            }
            #pragma unroll
            for (int j = 0; j < 4; ++j) { pbh[j] += 32768; pbl[j] += 32768; }
            __syncthreads();
        }
    }

    // ---- output layer: 64 dots of length 128 (two 64-channel halves) ----
    {
        const int st = tid & 63;
        const int hf = tid >> 6;
        const int db = st * HR + hf * 32;
        float part = 0.f;
        #pragma unroll
        for (int c4 = 0; c4 < 8; ++c4) {
            const bf16x8 hv = *(const bf16x8*)&Hhi[db + c4 * 4];
            const bf16x8 lv = *(const bf16x8*)&Hlo[db + c4 * 4];
            const float4 w1 = *(const float4*)&Wout[hf * 64 + c4 * 8];
            const float4 w2 = *(const float4*)&Wout[hf * 64 + c4 * 8 + 4];
            part = fmaf((float)hv[0] + (float)lv[0], w1.x, part);
            part = fmaf((float)hv[1] + (float)lv[1], w1.y, part);
            part = fmaf((float)hv[2] + (float)lv[2], w1.z, part);
            part = fmaf((float)hv[3] + (float)lv[3], w1.w, part);
            part = fmaf((float)hv[4] + (float)lv[4], w2.x, part);
            part = fmaf((float)hv[5] + (float)lv[5], w2.y, part);
            part = fmaf((float)hv[6] + (float)lv[6], w2.z, part);
            part = fmaf((float)hv[7] + (float)lv[7], w2.w, part);
        }
        pbuf[hf * 64 + st] = part;
    }
    __syncthreads();
    if (tid < 64) dots[tid] = pbuf[tid] + pbuf[64 + tid];
    __syncthreads();
    if (!isv) {
        if (tid < 16) {
            const float u = dots[tid] + bout[0];
            out[8192 + blk * 16 + tid] =
                dots[32 + tid] + u * dots[16 + tid] - NU_F * dots[48 + tid];
        }
    } else {
        if (tid < 64) out[(blk - 8192) * 64 + tid] = dots[tid] + bout[0];
    }
}

extern "C" void kernel_launch(void* const* d_in, const int* in_sizes, int n_in,
                              void* d_out, int out_size, void* d_ws, size_t ws_size,
                              hipStream_t stream) {
    (void)in_sizes; (void)n_in; (void)ws_size; (void)out_size;
    const float* xf   = (const float*)d_in[0];
    const float* x0   = (const float*)d_in[1];
    const float* xbl  = (const float*)d_in[2];
    const float* xbr  = (const float*)d_in[3];
    const float* Win  = (const float*)d_in[4];
    const float* bin  = (const float*)d_in[5];
    const float* Whid = (const float*)d_in[6];
    const float* bhid = (const float*)d_in[7];
    const float* Wout = (const float*)d_in[8];
    const float* bout = (const float*)d_in[9];
    float* out = (float*)d_out;

    __bf16* wcf = (__bf16*)d_ws;   // 7*128*128*2 bf16 = 448 KiB

    hipLaunchKernelGGL(prep_wfrag, dim3(114688 / 256), dim3(256), 0, stream,
                       Whid, wcf);
    hipLaunchKernelGGL(pinn_fused, dim3(8192 + 128), dim3(128), 0, stream,
                       xf, x0, xbl, xbr, Win, bin, bhid, Wout, bout, wcf, out);
}

// Round 6
// 413.319 us; speedup vs baseline: 1.0400x; 1.0400x over previous
//
#include <hip/hip_runtime.h>
#include <math.h>

#define NU_F 0.0031830988618379067f

typedef __bf16 bf16x8 __attribute__((ext_vector_type(8)));
typedef float  f32x4  __attribute__((ext_vector_type(4)));

__device__ __forceinline__ float fast_tanh(float z) {
    float e = __expf(2.0f * z);
    return 1.0f - 2.0f / (e + 1.0f);
}

// Pack truncated-bf16 hi halves of (a,b) -> one u32: {b.hi16, a.hi16}
__device__ __forceinline__ unsigned pack_hi(float a, float b) {
    return __builtin_amdgcn_perm(__float_as_uint(b), __float_as_uint(a), 0x07060302u);
}
// Pack bf16(lo) of (a,b) where lo = v - trunc16(v)
__device__ __forceinline__ unsigned pack_lo(float a, float b) {
    float ra = a - __uint_as_float(__float_as_uint(a) & 0xffff0000u);
    float rb = b - __uint_as_float(__float_as_uint(b) & 0xffff0000u);
    __bf16 la = (__bf16)ra, lb = (__bf16)rb;
    unsigned ua = (unsigned)*(unsigned short*)&la;
    unsigned ub = (unsigned)*(unsigned short*)&lb;
    return __builtin_amdgcn_perm(ub, ua, 0x05040100u);
}

// ---------------------------------------------------------------------------
// Prep: W_hid fp32 [7][128(k)][128(c)] -> bf16 hi/lo B-fragments, fragment-
// major (each wave-load = one coalesced 1 KiB block):
//   fid = ((l*8 + nt)*2 + hl)*4 + ks ; element = fid*512 + lane*8 + jj
//   k = ks*32 + q*8 + jj, lane = q*16 + nn
//   channel map: nt = ((c>>5)<<1)|(c&1), nn = (c>>1)&15  ->  c = wv*32+nn*2+j
// ---------------------------------------------------------------------------
__global__ void prep_wfrag(const float* __restrict__ Whid, __bf16* __restrict__ wcf)
{
    int t = blockIdx.x * 256 + threadIdx.x;   // 0 .. 114687
    const int l = t >> 14;
    const int r = t & 16383;
    const int k = r >> 7;
    const int c = r & 127;
    const float v = Whid[t];
    const __bf16 hi = (__bf16)v;
    const __bf16 lo = (__bf16)(v - (float)hi);
    const int ks = k >> 5, q = (k >> 3) & 3, jj = k & 7;
    const int nt = ((c >> 5) << 1) | (c & 1);
    const int nn = (c >> 1) & 15;
    const int lane = q * 16 + nn;
    const int base = (((l * 8 + nt) * 8) + ks) * 512 + lane * 8 + jj;  // hl=0
    wcf[base]        = hi;
    wcf[base + 2048] = lo;                                             // hl=1
}

#define HR 68
#define MFMA(A, B, C) __builtin_amdgcn_mfma_f32_16x16x32_bf16((A), (B), (C), 0, 0, 0)

// ---------------------------------------------------------------------------
// Derivative kernel: 16 points/block, 256 thr = 4 waves, wave -> N-tiles
// {2wv, 2wv+1}. Jet states (v,vx,vt,vxx) are the 4 M-tiles. H packed-u32 in
// LDS: Hhi 64 rows, Hlo only 48 rows (vxx lo == 0 always -> not stored).
// LDS total ~31.9 KiB -> 5 blocks/CU with __launch_bounds__(256,5).
// ---------------------------------------------------------------------------
__global__ __launch_bounds__(256, 5)
void pinn_deriv(const float* __restrict__ xf,
                const float* __restrict__ Win,  const float* __restrict__ bin,
                const float* __restrict__ bhid,
                const float* __restrict__ Wout, const float* __restrict__ bout,
                const __bf16* __restrict__ wcf,
                float* __restrict__ out)
{
    __shared__ unsigned Hhi[64 * HR];
    __shared__ unsigned Hlo[48 * HR];
    __shared__ float xpt[32];
    __shared__ float pbuf[256];
    __shared__ float dots[64];

    const int tid  = threadIdx.x;
    const int lane = tid & 63;
    const int wv   = tid >> 6;
    const int lm   = lane & 15;
    const int lq   = lane >> 4;
    const int blk  = blockIdx.x;

    if (tid < 32) xpt[tid] = xf[blk * 32 + tid];
    __syncthreads();

    // ---- input layer: thread owns channel pair c0=2*(tid&63) ----
    const int cp = tid & 63;
    {
        const float2 w01 = *(const float2*)&Win[cp * 2];
        const float2 w11 = *(const float2*)&Win[128 + cp * 2];
        const float2 bb  = *(const float2*)&bin[cp * 2];
        const int p0 = (tid >> 6) * 4;
        #pragma unroll
        for (int i = 0; i < 4; ++i) {
            const int p = p0 + i;
            const float x = xpt[2 * p], tt = xpt[2 * p + 1];
            const float za = fmaf(x, w01.x, fmaf(tt, w11.x, bb.x));
            const float zb = fmaf(x, w01.y, fmaf(tt, w11.y, bb.y));
            const float ya = fast_tanh(za), yb = fast_tanh(zb);
            const float da = 1.f - ya * ya, db = 1.f - yb * yb;
            const float v1a = da * w01.x, v1b = db * w01.y;
            const float v2a = da * w11.x, v2b = db * w11.y;
            const float v3a = -2.f * ya * da * w01.x * w01.x;
            const float v3b = -2.f * yb * db * w01.y * w01.y;
            Hhi[(0 * 16 + p) * HR + cp] = pack_hi(ya, yb);
            Hhi[(1 * 16 + p) * HR + cp] = pack_hi(v1a, v1b);
            Hhi[(2 * 16 + p) * HR + cp] = pack_hi(v2a, v2b);
            Hhi[(3 * 16 + p) * HR + cp] = pack_hi(v3a, v3b);
            Hlo[(0 * 16 + p) * HR + cp] = pack_lo(ya, yb);
            Hlo[(1 * 16 + p) * HR + cp] = pack_lo(v1a, v1b);
            Hlo[(2 * 16 + p) * HR + cp] = pack_lo(v2a, v2b);
        }
    }
    __syncthreads();

    // B-fragment pointers (coalesced: lane*8 within each 512-elem fragment).
    const __bf16* pb0h = wcf + (wv * 2 + 0) * 4096 + lane * 8;
    const __bf16* pb0l = pb0h + 2048;
    const __bf16* pb1h = wcf + (wv * 2 + 1) * 4096 + lane * 8;
    const __bf16* pb1l = pb1h + 2048;
    const float2* bh2 = (const float2*)bhid + (wv * 16 + lm);
    const int wc = wv * 16 + lm;   // epilogue dword column

    for (int l = 0; l < 7; ++l) {
        f32x4 acc[4][2];
        #pragma unroll
        for (int s = 0; s < 4; ++s)
            #pragma unroll
            for (int j = 0; j < 2; ++j) acc[s][j] = (f32x4){0.f, 0.f, 0.f, 0.f};

        #pragma unroll
        for (int ks = 0; ks < 4; ++ks) {
            const int ro = ks * 16 + lq * 4;
            const bf16x8 ah0 = *(const bf16x8*)&Hhi[(0 * 16 + lm) * HR + ro];
            const bf16x8 ah1 = *(const bf16x8*)&Hhi[(1 * 16 + lm) * HR + ro];
            const bf16x8 ah2 = *(const bf16x8*)&Hhi[(2 * 16 + lm) * HR + ro];
            const bf16x8 ah3 = *(const bf16x8*)&Hhi[(3 * 16 + lm) * HR + ro];
            const bf16x8 al0 = *(const bf16x8*)&Hlo[(0 * 16 + lm) * HR + ro];
            const bf16x8 al1 = *(const bf16x8*)&Hlo[(1 * 16 + lm) * HR + ro];
            const bf16x8 al2 = *(const bf16x8*)&Hlo[(2 * 16 + lm) * HR + ro];
            const bf16x8 bh0 = *(const bf16x8*)(pb0h + ks * 512);
            const bf16x8 bl0 = *(const bf16x8*)(pb0l + ks * 512);
            const bf16x8 bh1 = *(const bf16x8*)(pb1h + ks * 512);
            const bf16x8 bl1 = *(const bf16x8*)(pb1l + ks * 512);
            acc[0][0] = MFMA(ah0, bh0, acc[0][0]);
            acc[0][0] = MFMA(ah0, bl0, acc[0][0]);
            acc[0][0] = MFMA(al0, bh0, acc[0][0]);
            acc[1][0] = MFMA(ah1, bh0, acc[1][0]);
            acc[1][0] = MFMA(ah1, bl0, acc[1][0]);
            acc[1][0] = MFMA(al1, bh0, acc[1][0]);
            acc[2][0] = MFMA(ah2, bh0, acc[2][0]);
            acc[2][0] = MFMA(ah2, bl0, acc[2][0]);
            acc[2][0] = MFMA(al2, bh0, acc[2][0]);
            acc[3][0] = MFMA(ah3, bh0, acc[3][0]);
            acc[3][0] = MFMA(ah3, bl0, acc[3][0]);
            acc[0][1] = MFMA(ah0, bh1, acc[0][1]);
            acc[0][1] = MFMA(ah0, bl1, acc[0][1]);
            acc[0][1] = MFMA(al0, bh1, acc[0][1]);
            acc[1][1] = MFMA(ah1, bh1, acc[1][1]);
            acc[1][1] = MFMA(ah1, bl1, acc[1][1]);
            acc[1][1] = MFMA(al1, bh1, acc[1][1]);
            acc[2][1] = MFMA(ah2, bh1, acc[2][1]);
            acc[2][1] = MFMA(ah2, bl1, acc[2][1]);
            acc[2][1] = MFMA(al2, bh1, acc[2][1]);
            acc[3][1] = MFMA(ah3, bh1, acc[3][1]);
            acc[3][1] = MFMA(ah3, bl1, acc[3][1]);
        }
        __syncthreads();

        const float2 bb = bh2[l * 64];
        #pragma unroll
        for (int r = 0; r < 4; ++r) {
            const int p = lq * 4 + r;
            float h[2][4];
            #pragma unroll
            for (int j = 0; j < 2; ++j) {
                const float zv  = acc[0][j][r] + (j ? bb.y : bb.x);
                const float zx  = acc[1][j][r];
                const float zt  = acc[2][j][r];
                const float zxx = acc[3][j][r];
                const float y = fast_tanh(zv);
                const float d = 1.f - y * y;
                h[j][0] = y;
                h[j][1] = d * zx;
                h[j][2] = d * zt;
                h[j][3] = fmaf(d, zxx, -2.f * y * d * zx * zx);
            }
            Hhi[(0 * 16 + p) * HR + wc] = pack_hi(h[0][0], h[1][0]);
            Hhi[(1 * 16 + p) * HR + wc] = pack_hi(h[0][1], h[1][1]);
            Hhi[(2 * 16 + p) * HR + wc] = pack_hi(h[0][2], h[1][2]);
            Hhi[(3 * 16 + p) * HR + wc] = pack_hi(h[0][3], h[1][3]);
            Hlo[(0 * 16 + p) * HR + wc] = pack_lo(h[0][0], h[1][0]);
            Hlo[(1 * 16 + p) * HR + wc] = pack_lo(h[0][1], h[1][1]);
            Hlo[(2 * 16 + p) * HR + wc] = pack_lo(h[0][2], h[1][2]);
        }
        pb0h += 32768; pb0l += 32768; pb1h += 32768; pb1l += 32768;
        __syncthreads();
    }

    // ---- output layer: 64 dots (4 states x 16 pts) of length 128 ----
    {
        const int st = tid & 63;
        const int ch = tid >> 6;      // 16 dwords (32 channels) per chunk
        const int cb = ch * 16;
        float part = 0.f;
        #pragma unroll
        for (int c8 = 0; c8 < 4; ++c8) {
            const bf16x8 hv = *(const bf16x8*)&Hhi[st * HR + cb + c8 * 4];
            const float4 w1 = *(const float4*)&Wout[cb * 2 + c8 * 8];
            const float4 w2 = *(const float4*)&Wout[cb * 2 + c8 * 8 + 4];
            part = fmaf((float)hv[0], w1.x, part);
            part = fmaf((float)hv[1], w1.y, part);
            part = fmaf((float)hv[2], w1.z, part);
            part = fmaf((float)hv[3], w1.w, part);
            part = fmaf((float)hv[4], w2.x, part);
            part = fmaf((float)hv[5], w2.y, part);
            part = fmaf((float)hv[6], w2.z, part);
            part = fmaf((float)hv[7], w2.w, part);
        }
        if (st < 48) {   // lo contribution (vxx has no lo)
            #pragma unroll
            for (int c8 = 0; c8 < 4; ++c8) {
                const bf16x8 lv = *(const bf16x8*)&Hlo[st * HR + cb + c8 * 4];
                const float4 w1 = *(const float4*)&Wout[cb * 2 + c8 * 8];
                const float4 w2 = *(const float4*)&Wout[cb * 2 + c8 * 8 + 4];
                part = fmaf((float)lv[0], w1.x, part);
                part = fmaf((float)lv[1], w1.y, part);
                part = fmaf((float)lv[2], w1.z, part);
                part = fmaf((float)lv[3], w1.w, part);
                part = fmaf((float)lv[4], w2.x, part);
                part = fmaf((float)lv[5], w2.y, part);
                part = fmaf((float)lv[6], w2.z, part);
                part = fmaf((float)lv[7], w2.w, part);
            }
        }
        pbuf[ch * 64 + st] = part;
    }
    __syncthreads();
    if (tid < 64)
        dots[tid] = pbuf[tid] + pbuf[64 + tid] + pbuf[128 + tid] + pbuf[192 + tid];
    __syncthreads();
    if (tid < 16) {
        const float u = dots[tid] + bout[0];
        out[8192 + blk * 16 + tid] =
            dots[32 + tid] + u * dots[16 + tid] - NU_F * dots[48 + tid];
    }
}

// ---------------------------------------------------------------------------
// Value-only kernel: 64 points/block (4 M-tiles of points), 128 blocks.
// Same GEMM structure; own full-size hi/lo LDS.
// ---------------------------------------------------------------------------
__global__ __launch_bounds__(256, 4)
void pinn_value(const float* __restrict__ x0,  const float* __restrict__ xbl,
                const float* __restrict__ xbr,
                const float* __restrict__ Win,  const float* __restrict__ bin,
                const float* __restrict__ bhid,
                const float* __restrict__ Wout, const float* __restrict__ bout,
                const __bf16* __restrict__ wcf,
                float* __restrict__ out)
{
    __shared__ unsigned Hhi[64 * HR];
    __shared__ unsigned Hlo[64 * HR];
    __shared__ float xpt[128];
    __shared__ float pbuf[256];
    __shared__ float dots[64];

    const int tid  = threadIdx.x;
    const int lane = tid & 63;
    const int wv   = tid >> 6;
    const int lm   = lane & 15;
    const int lq   = lane >> 4;
    const int vb   = blockIdx.x;

    const float* src = (vb < 64) ? (x0 + vb * 128)
                     : (vb < 96) ? (xbl + (vb - 64) * 128)
                                 : (xbr + (vb - 96) * 128);
    if (tid < 128) xpt[tid] = src[tid];
    __syncthreads();

    const int cp = tid & 63;
    {
        const float2 w01 = *(const float2*)&Win[cp * 2];
        const float2 w11 = *(const float2*)&Win[128 + cp * 2];
        const float2 bb  = *(const float2*)&bin[cp * 2];
        const int p0 = (tid >> 6) * 16;
        #pragma unroll
        for (int i = 0; i < 16; ++i) {
            const int p = p0 + i;
            const float x = xpt[2 * p], tt = xpt[2 * p + 1];
            const float za = fmaf(x, w01.x, fmaf(tt, w11.x, bb.x));
            const float zb = fmaf(x, w01.y, fmaf(tt, w11.y, bb.y));
            const float ya = fast_tanh(za), yb = fast_tanh(zb);
            Hhi[p * HR + cp] = pack_hi(ya, yb);
            Hlo[p * HR + cp] = pack_lo(ya, yb);
        }
    }
    __syncthreads();

    const __bf16* pb0h = wcf + (wv * 2 + 0) * 4096 + lane * 8;
    const __bf16* pb0l = pb0h + 2048;
    const __bf16* pb1h = wcf + (wv * 2 + 1) * 4096 + lane * 8;
    const __bf16* pb1l = pb1h + 2048;
    const float2* bh2 = (const float2*)bhid + (wv * 16 + lm);
    const int wc = wv * 16 + lm;

    for (int l = 0; l < 7; ++l) {
        f32x4 acc[4][2];
        #pragma unroll
        for (int mt = 0; mt < 4; ++mt)
            #pragma unroll
            for (int j = 0; j < 2; ++j) acc[mt][j] = (f32x4){0.f, 0.f, 0.f, 0.f};

        #pragma unroll
        for (int ks = 0; ks < 4; ++ks) {
            const int ro = ks * 16 + lq * 4;
            bf16x8 ah[4], al[4];
            #pragma unroll
            for (int mt = 0; mt < 4; ++mt) {
                ah[mt] = *(const bf16x8*)&Hhi[(mt * 16 + lm) * HR + ro];
                al[mt] = *(const bf16x8*)&Hlo[(mt * 16 + lm) * HR + ro];
            }
            const bf16x8 bh0 = *(const bf16x8*)(pb0h + ks * 512);
            const bf16x8 bl0 = *(const bf16x8*)(pb0l + ks * 512);
            const bf16x8 bh1 = *(const bf16x8*)(pb1h + ks * 512);
            const bf16x8 bl1 = *(const bf16x8*)(pb1l + ks * 512);
            #pragma unroll
            for (int mt = 0; mt < 4; ++mt) {
                acc[mt][0] = MFMA(ah[mt], bh0, acc[mt][0]);
                acc[mt][0] = MFMA(ah[mt], bl0, acc[mt][0]);
                acc[mt][0] = MFMA(al[mt], bh0, acc[mt][0]);
                acc[mt][1] = MFMA(ah[mt], bh1, acc[mt][1]);
                acc[mt][1] = MFMA(ah[mt], bl1, acc[mt][1]);
                acc[mt][1] = MFMA(al[mt], bh1, acc[mt][1]);
            }
        }
        __syncthreads();

        const float2 bb = bh2[l * 64];
        #pragma unroll
        for (int mt = 0; mt < 4; ++mt) {
            #pragma unroll
            for (int r = 0; r < 4; ++r) {
                const int p = mt * 16 + lq * 4 + r;
                const float ya = fast_tanh(acc[mt][0][r] + bb.x);
                const float yb = fast_tanh(acc[mt][1][r] + bb.y);
                Hhi[p * HR + wc] = pack_hi(ya, yb);
                Hlo[p * HR + wc] = pack_lo(ya, yb);
            }
        }
        pb0h += 32768; pb0l += 32768; pb1h += 32768; pb1l += 32768;
        __syncthreads();
    }

    {
        const int st = tid & 63;
        const int ch = tid >> 6;
        const int cb = ch * 16;
        float part = 0.f;
        #pragma unroll
        for (int c8 = 0; c8 < 4; ++c8) {
            const bf16x8 hv = *(const bf16x8*)&Hhi[st * HR + cb + c8 * 4];
            const bf16x8 lv = *(const bf16x8*)&Hlo[st * HR + cb + c8 * 4];
            const float4 w1 = *(const float4*)&Wout[cb * 2 + c8 * 8];
            const float4 w2 = *(const float4*)&Wout[cb * 2 + c8 * 8 + 4];
            part = fmaf((float)hv[0] + (float)lv[0], w1.x, part);
            part = fmaf((float)hv[1] + (float)lv[1], w1.y, part);
            part = fmaf((float)hv[2] + (float)lv[2], w1.z, part);
            part = fmaf((float)hv[3] + (float)lv[3], w1.w, part);
            part = fmaf((float)hv[4] + (float)lv[4], w2.x, part);
            part = fmaf((float)hv[5] + (float)lv[5], w2.y, part);
            part = fmaf((float)hv[6] + (float)lv[6], w2.z, part);
            part = fmaf((float)hv[7] + (float)lv[7], w2.w, part);
        }
        pbuf[ch * 64 + st] = part;
    }
    __syncthreads();
    if (tid < 64)
        dots[tid] = pbuf[tid] + pbuf[64 + tid] + pbuf[128 + tid] + pbuf[192 + tid];
    __syncthreads();
    if (tid < 64) out[vb * 64 + tid] = dots[tid] + bout[0];
}

extern "C" void kernel_launch(void* const* d_in, const int* in_sizes, int n_in,
                              void* d_out, int out_size, void* d_ws, size_t ws_size,
                              hipStream_t stream) {
    (void)in_sizes; (void)n_in; (void)ws_size; (void)out_size;
    const float* xf   = (const float*)d_in[0];
    const float* x0   = (const float*)d_in[1];
    const float* xbl  = (const float*)d_in[2];
    const float* xbr  = (const float*)d_in[3];
    const float* Win  = (const float*)d_in[4];
    const float* bin  = (const float*)d_in[5];
    const float* Whid = (const float*)d_in[6];
    const float* bhid = (const float*)d_in[7];
    const float* Wout = (const float*)d_in[8];
    const float* bout = (const float*)d_in[9];
    float* out = (float*)d_out;

    __bf16* wcf = (__bf16*)d_ws;   // 7*128*128*2 bf16 = 448 KiB

    hipLaunchKernelGGL(prep_wfrag, dim3(114688 / 256), dim3(256), 0, stream,
                       Whid, wcf);
    hipLaunchKernelGGL(pinn_value, dim3(128), dim3(256), 0, stream,
                       x0, xbl, xbr, Win, bin, bhid, Wout, bout, wcf, out);
    hipLaunchKernelGGL(pinn_deriv, dim3(8192), dim3(256), 0, stream,
                       xf, Win, bin, bhid, Wout, bout, wcf, out);
}